// Round 5
// baseline (1211.980 us; speedup 1.0000x reference)
//
#include <hip/hip_runtime.h>
#include <hip/hip_bf16.h>
#include <cstdint>

#define BB 64
#define HH 128
#define WW 2048
#define UNITS 32
#define VOCAB 201
#define L2E 1.4426950408889634f

__device__ __forceinline__ float rcp_fast(float x) {
#if __has_builtin(__builtin_amdgcn_rcpf)
  return __builtin_amdgcn_rcpf(x);
#else
  return 1.0f / x;
#endif
}
__device__ __forceinline__ float exp2_fast(float x) {
#if __has_builtin(__builtin_amdgcn_exp2f)
  return __builtin_amdgcn_exp2f(x);
#else
  return exp2f(x);
#endif
}
__device__ __forceinline__ float rdlane(float v, int l) {
#if __has_builtin(__builtin_amdgcn_readlane)
  return __int_as_float(__builtin_amdgcn_readlane(__float_as_int(v), l));
#else
  return __shfl(v, l, 64);
#endif
}

// ---------------------------------------------------------------- conv 5x5
__global__ void k_conv(const float* __restrict__ x, const float* __restrict__ ck,
                       const int* __restrict__ widths, float* __restrict__ h) {
  const int b = blockIdx.z, y = blockIdx.y;
  const int x0 = blockIdx.x * 256;
  if (x0 >= widths[b]) return;  // outputs past width are never consumed
  const int tx = threadIdx.x;
  __shared__ float tile[5][260];
  const float* xb = x + (size_t)b * HH * WW;
#pragma unroll
  for (int r = 0; r < 5; ++r) {
    const int yy = y + r - 2;
    for (int c = tx; c < 260; c += 256) {
      const int xx = x0 - 2 + c;
      float v = 0.f;
      if (yy >= 0 && yy < HH && xx >= 0 && xx < WW) v = xb[(size_t)yy * WW + xx];
      tile[r][c] = v;
    }
  }
  __syncthreads();
  float acc = 0.f;
#pragma unroll
  for (int r = 0; r < 5; ++r)
#pragma unroll
    for (int c = 0; c < 5; ++c)
      acc = fmaf(tile[r][tx + c], ck[r * 5 + c], acc);
  h[((size_t)b * HH + y) * WW + x0 + tx] = acc;
}

// ------------------------------------------- xw = seq^T * [Wf|Wb] + bias
// M = t (64/tile), N = gate (64/tile of 256), K = f = 128 (fully staged)
__global__ __launch_bounds__(256, 2) void k_xw(
    const float* __restrict__ h, const float* __restrict__ Wf,
    const float* __restrict__ Wb, const float* __restrict__ bf,
    const float* __restrict__ bb, const int* __restrict__ widths,
    float* __restrict__ xw) {
  const int b = blockIdx.z;
  const int t0 = blockIdx.y * 64;
  if (t0 >= widths[b]) return;  // recurrence only reads t < width
  const int g0 = blockIdx.x * 64;
  __shared__ __align__(16) float ht[128][64];
  __shared__ __align__(16) float wt[128][64];
  const int tid = threadIdx.x;
  const float* __restrict__ Wsrc = (g0 < 128) ? (Wf + g0) : (Wb + (g0 - 128));
  const float* __restrict__ bsrc = (g0 < 128) ? (bf + g0) : (bb + (g0 - 128));
  const float* hb = h + (size_t)b * HH * WW + t0;
#pragma unroll
  for (int i = 0; i < 8; ++i) {
    const int idx = tid + i * 256;  // 0..2047
    const int row = idx >> 4, c4 = (idx & 15) * 4;
    *(float4*)&ht[row][c4] = *(const float4*)&hb[(size_t)row * WW + c4];
    *(float4*)&wt[row][c4] = *(const float4*)&Wsrc[row * 128 + c4];
  }
  __syncthreads();
  const int tg = (tid & 15) * 4;
  const int tt = (tid >> 4) * 4;
  float acc[4][4];
#pragma unroll
  for (int i = 0; i < 4; ++i)
#pragma unroll
    for (int j = 0; j < 4; ++j) acc[i][j] = 0.f;
#pragma unroll 8
  for (int k = 0; k < 128; ++k) {
    const float4 av = *(const float4*)&ht[k][tt];
    const float4 wv = *(const float4*)&wt[k][tg];
    const float aarr[4] = {av.x, av.y, av.z, av.w};
    const float warr[4] = {wv.x, wv.y, wv.z, wv.w};
#pragma unroll
    for (int i = 0; i < 4; ++i)
#pragma unroll
      for (int j = 0; j < 4; ++j) acc[i][j] = fmaf(aarr[i], warr[j], acc[i][j]);
  }
  const float4 bias = *(const float4*)&bsrc[tg];
#pragma unroll
  for (int i = 0; i < 4; ++i) {
    float4 r;
    r.x = acc[i][0] + bias.x;
    r.y = acc[i][1] + bias.y;
    r.z = acc[i][2] + bias.z;
    r.w = acc[i][3] + bias.w;
    *(float4*)&xw[((size_t)b * WW + t0 + tt + i) * 256 + g0 + tg] = r;
  }
}

// -------------------------------------------------------- LSTM recurrence
// One wave per (batch, direction) chain. Lane j owns gate columns j and j+64.
// Gate layout in z[128]: [i(0:32) f(32:64) g(64:96) o(96:128)].
// low lane u: z1=i_u, z2=g_u ; high lane u+32: z1=f_u, z2=o_u.
// NO lambdas / address-taking: round-4 counters showed lambda ref-capture
// demoted u1/u2/hk to scratch (VGPR=52, FETCH=32 GB). Macros keep every
// array statically indexed and register-resident.
__global__ __launch_bounds__(64, 1) void k_lstm(
    const float* __restrict__ xw, const float* __restrict__ Uf,
    const float* __restrict__ Ub, const int* __restrict__ widths,
    float* __restrict__ outF, float* __restrict__ outB) {
  const int chain = blockIdx.x;
  const int b = chain >> 1, dir = chain & 1;
  const int width = widths[b];
  const int lane = threadIdx.x;
  const bool low = lane < 32;
  const float* __restrict__ U = dir ? Ub : Uf;
  float u1[UNITS], u2[UNITS];
#pragma unroll
  for (int k = 0; k < UNITS; ++k) {
    u1[k] = U[k * 128 + lane];
    u2[k] = U[k * 128 + 64 + lane];
  }
  // s2 activation: low = tanh (2*sig(2x)-1), high = sigmoid
  const float M2 = low ? (-2.f * L2E) : (-L2E);
  const float A2 = low ? 2.f : 1.f;
  const float B2 = low ? -1.f : 0.f;
  float* __restrict__ outp = dir ? outB : outF;

  const int t_first = dir ? (width - 1) : 0;
  const long sstep = dir ? -256 : 256;  // xw elements per time step
  const float* p0 = xw + ((size_t)b * WW) * 256 + dir * 128 + lane + (long)t_first * 256;

  float c = 0.f, hv = 0.f;
  float hs[UNITS];  // wave-uniform (readlane results) -> SGPRs
#pragma unroll
  for (int k = 0; k < UNITS; ++k) hs[k] = 0.f;

  float A0[4], B0[4], A1[4], B1[4];

#define LOADG(Aa, Bb, gg)                                   \
  do {                                                      \
    const float* pg_ = p0 + (long)((gg) * 4) * sstep;       \
    _Pragma("unroll") for (int i_ = 0; i_ < 4; ++i_) {      \
      (Aa)[i_] = pg_[0];                                    \
      (Bb)[i_] = pg_[64];                                   \
      pg_ += sstep;                                         \
    }                                                       \
  } while (0)

#define STEP1(Ai, Bi, ss)                                                     \
  do {                                                                        \
    if ((ss) < width) { /* wave-uniform */                                    \
      float s00 = 0.f, s01 = 0.f, s02 = 0.f, s03 = 0.f;                       \
      float s10 = 0.f, s11 = 0.f, s12 = 0.f, s13 = 0.f;                       \
      _Pragma("unroll") for (int k_ = 0; k_ < UNITS; k_ += 4) {               \
        s00 = fmaf(hs[k_ + 0], u1[k_ + 0], s00);                              \
        s01 = fmaf(hs[k_ + 1], u1[k_ + 1], s01);                              \
        s02 = fmaf(hs[k_ + 2], u1[k_ + 2], s02);                              \
        s03 = fmaf(hs[k_ + 3], u1[k_ + 3], s03);                              \
        s10 = fmaf(hs[k_ + 0], u2[k_ + 0], s10);                              \
        s11 = fmaf(hs[k_ + 1], u2[k_ + 1], s11);                              \
        s12 = fmaf(hs[k_ + 2], u2[k_ + 2], s12);                              \
        s13 = fmaf(hs[k_ + 3], u2[k_ + 3], s13);                              \
      }                                                                       \
      const float z1 = (Ai) + ((s00 + s01) + (s02 + s03));                    \
      const float z2 = (Bi) + ((s10 + s11) + (s12 + s13));                    \
      const float sg1 = rcp_fast(1.f + exp2_fast(z1 * (-L2E)));               \
      const float r2_ = rcp_fast(1.f + exp2_fast(z2 * M2));                   \
      const float sg2 = fmaf(A2, r2_, B2);                                    \
      const float t1_ = __shfl_xor(sg1, 32, 64);                              \
      const float t2_ = __shfl_xor(sg2, 32, 64);                              \
      const float gi_ = low ? sg1 : t1_;                                      \
      const float gf_ = low ? t1_ : sg1;                                      \
      const float gg_ = low ? sg2 : t2_;                                      \
      const float go_ = low ? t2_ : sg2;                                      \
      c = fmaf(gf_, c, gi_ * gg_);                                            \
      const float th_ =                                                       \
          fmaf(2.f, rcp_fast(1.f + exp2_fast(c * (-2.f * L2E))), -1.f);       \
      hv = go_ * th_;                                                         \
      const int t_ = dir ? (width - 1 - (ss)) : (ss);                         \
      if (low) outp[((size_t)b * WW + t_) * UNITS + lane] = hv;               \
      _Pragma("unroll") for (int k_ = 0; k_ < UNITS; ++k_) hs[k_] =           \
          rdlane(hv, k_);                                                     \
    }                                                                         \
  } while (0)

#define STEPS4(Aa, Bb, gg)              \
  do {                                  \
    STEP1((Aa)[0], (Bb)[0], (gg)*4+0);  \
    STEP1((Aa)[1], (Bb)[1], (gg)*4+1);  \
    STEP1((Aa)[2], (Bb)[2], (gg)*4+2);  \
    STEP1((Aa)[3], (Bb)[3], (gg)*4+3);  \
  } while (0)

  const int ngroups = (width + 3) >> 2;
  LOADG(A0, B0, 0);
  for (int g = 0; g < ngroups; g += 2) {
    if (g + 1 < ngroups) LOADG(A1, B1, g + 1);
    STEPS4(A0, B0, g);
    if (g + 1 < ngroups) {
      if (g + 2 < ngroups) LOADG(A0, B0, g + 2);
      STEPS4(A1, B1, g + 1);
    }
  }
#undef LOADG
#undef STEP1
#undef STEPS4
}

// ------------------------------------------- dense(32->201) + softmax + mask
__global__ __launch_bounds__(256, 1) void k_dense(
    const float* __restrict__ outF, const float* __restrict__ outB,
    const float* __restrict__ Wd, const float* __restrict__ bd,
    const int* __restrict__ widths, float* __restrict__ out) {
  const int lane = threadIdx.x & 63;
  const int gw = (int)((blockIdx.x * blockDim.x + threadIdx.x) >> 6);
  const int nw = (int)((gridDim.x * blockDim.x) >> 6);
  const int v0 = lane, v1 = lane + 64, v2 = lane + 128, v3 = lane + 192;
  const bool val3 = v3 < VOCAB;
  float w0[UNITS], w1[UNITS], w2[UNITS], w3[UNITS];
#pragma unroll
  for (int k = 0; k < UNITS; ++k) {
    w0[k] = Wd[k * VOCAB + v0];
    w1[k] = Wd[k * VOCAB + v1];
    w2[k] = Wd[k * VOCAB + v2];
    w3[k] = val3 ? Wd[k * VOCAB + v3] : 0.f;
  }
  const float b0 = bd[v0], b1 = bd[v1], b2 = bd[v2], b3 = val3 ? bd[v3] : 0.f;
  const int total = BB * WW;
  for (int t = gw; t < total; t += nw) {
    const int bb_ = t >> 11, tt = t & (WW - 1);
    float* o = out + (size_t)t * VOCAB;
    if (tt >= widths[bb_]) {
      o[v0] = 0.f; o[v1] = 0.f; o[v2] = 0.f;
      if (val3) o[v3] = 0.f;
      continue;
    }
    float mk = 0.f;
    if (lane < UNITS)
      mk = outF[(size_t)t * UNITS + lane] + outB[(size_t)t * UNITS + lane];
    float l0 = b0, l1 = b1, l2 = b2, l3 = b3;
#pragma unroll
    for (int k = 0; k < UNITS; ++k) {
      const float hkk = rdlane(mk, k);
      l0 = fmaf(hkk, w0[k], l0);
      l1 = fmaf(hkk, w1[k], l1);
      l2 = fmaf(hkk, w2[k], l2);
      l3 = fmaf(hkk, w3[k], l3);
    }
    if (!val3) l3 = -3.0e38f;
    float mx = fmaxf(fmaxf(l0, l1), fmaxf(l2, l3));
#pragma unroll
    for (int off = 32; off >= 1; off >>= 1) mx = fmaxf(mx, __shfl_xor(mx, off, 64));
    const float e0 = exp2_fast((l0 - mx) * L2E);
    const float e1 = exp2_fast((l1 - mx) * L2E);
    const float e2 = exp2_fast((l2 - mx) * L2E);
    const float e3 = val3 ? exp2_fast((l3 - mx) * L2E) : 0.f;
    float s = ((e0 + e1) + (e2 + e3));
#pragma unroll
    for (int off = 32; off >= 1; off >>= 1) s += __shfl_xor(s, off, 64);
    const float r = rcp_fast(s);
    o[v0] = e0 * r;
    o[v1] = e1 * r;
    o[v2] = e2 * r;
    if (val3) o[v3] = e3 * r;
  }
}

extern "C" void kernel_launch(void* const* d_in, const int* in_sizes, int n_in,
                              void* d_out, int out_size, void* d_ws, size_t ws_size,
                              hipStream_t stream) {
  const float* x  = (const float*)d_in[0];
  const float* ck = (const float*)d_in[1];
  const float* Wf = (const float*)d_in[2];
  const float* Uf = (const float*)d_in[3];
  const float* bf = (const float*)d_in[4];
  const float* Wb = (const float*)d_in[5];
  const float* Ub = (const float*)d_in[6];
  const float* bb = (const float*)d_in[7];
  const float* Wd = (const float*)d_in[8];
  const float* bd = (const float*)d_in[9];
  const int* widths = (const int*)d_in[10];
  float* out = (float*)d_out;
  char* ws = (char*)d_ws;
  // ws layout (fp32): h_conv 64MiB | xw 128MiB | out_f 16MiB | out_b 16MiB
  float* h  = (float*)(ws);
  float* xw = (float*)(ws + 67108864);
  float* oF = (float*)(ws + 67108864 + 134217728);
  float* oB = (float*)(ws + 67108864 + 134217728 + 16777216);

  k_conv<<<dim3(WW / 256, HH, BB), 256, 0, stream>>>(x, ck, widths, h);
  k_xw<<<dim3(4, WW / 64, BB), 256, 0, stream>>>(h, Wf, Wb, bf, bb, widths, xw);
  k_lstm<<<dim3(2 * BB), 64, 0, stream>>>(xw, Uf, Ub, widths, oF, oB);
  k_dense<<<dim3(1024), 256, 0, stream>>>(oF, oB, Wd, bd, widths, out);
}

// Round 7
// 1122.465 us; speedup vs baseline: 1.0797x; 1.0797x over previous
//
#include <hip/hip_runtime.h>
#include <hip/hip_bf16.h>
#include <cstdint>

#define BB 64
#define HH 128
#define WW 2048
#define UNITS 32
#define VOCAB 201
#define L2E 1.4426950408889634f

__device__ __forceinline__ float rcp_fast(float x) {
#if __has_builtin(__builtin_amdgcn_rcpf)
  return __builtin_amdgcn_rcpf(x);
#else
  return 1.0f / x;
#endif
}
__device__ __forceinline__ float exp2_fast(float x) {
#if __has_builtin(__builtin_amdgcn_exp2f)
  return __builtin_amdgcn_exp2f(x);
#else
  return exp2f(x);
#endif
}
__device__ __forceinline__ float rdlane(float v, int l) {
#if __has_builtin(__builtin_amdgcn_readlane)
  return __int_as_float(__builtin_amdgcn_readlane(__float_as_int(v), l));
#else
  return __shfl(v, l, 64);
#endif
}

// halfswap: given per-lane values a,b produce
//   x = [b.hi | a.hi]  (lanes 0-31: b from lane+32 ; lanes 32-63: own a)
//   y = [b.lo | a.lo]  (lanes 0-31: own b         ; lanes 32-63: a from lane-32)
// via v_permlane32_swap (VALU) or shfl fallback (identical semantics).
__device__ __forceinline__ void halfswap(float a, float b, float& x, float& y) {
#if __has_builtin(__builtin_amdgcn_permlane32_swap)
  auto r = __builtin_amdgcn_permlane32_swap(__float_as_uint(a), __float_as_uint(b),
                                            false, false);
  x = __uint_as_float(r[0]);
  y = __uint_as_float(r[1]);
#else
  const bool low_ = (threadIdx.x & 63) < 32;
  const float ta = __shfl_xor(a, 32, 64);
  const float tb = __shfl_xor(b, 32, 64);
  x = low_ ? tb : a;
  y = low_ ? b : ta;
#endif
}

#define REP32(M)                                                              \
  M(0) M(1) M(2) M(3) M(4) M(5) M(6) M(7) M(8) M(9) M(10) M(11) M(12) M(13)  \
  M(14) M(15) M(16) M(17) M(18) M(19) M(20) M(21) M(22) M(23) M(24) M(25)    \
  M(26) M(27) M(28) M(29) M(30) M(31)

// ---------------------------------------------------------------- conv 5x5
__global__ void k_conv(const float* __restrict__ x, const float* __restrict__ ck,
                       const int* __restrict__ widths, float* __restrict__ h) {
  const int b = blockIdx.z, y = blockIdx.y;
  const int x0 = blockIdx.x * 256;
  if (x0 >= widths[b]) return;  // outputs past width are never consumed
  const int tx = threadIdx.x;
  __shared__ float tile[5][260];
  const float* xb = x + (size_t)b * HH * WW;
#pragma unroll
  for (int r = 0; r < 5; ++r) {
    const int yy = y + r - 2;
    for (int c = tx; c < 260; c += 256) {
      const int xx = x0 - 2 + c;
      float v = 0.f;
      if (yy >= 0 && yy < HH && xx >= 0 && xx < WW) v = xb[(size_t)yy * WW + xx];
      tile[r][c] = v;
    }
  }
  __syncthreads();
  float acc = 0.f;
#pragma unroll
  for (int r = 0; r < 5; ++r)
#pragma unroll
    for (int c = 0; c < 5; ++c)
      acc = fmaf(tile[r][tx + c], ck[r * 5 + c], acc);
  h[((size_t)b * HH + y) * WW + x0 + tx] = acc;
}

// ------------------------------------------- xw = seq^T * [Wf|Wb] + bias
__global__ __launch_bounds__(256, 2) void k_xw(
    const float* __restrict__ h, const float* __restrict__ Wf,
    const float* __restrict__ Wb, const float* __restrict__ bf,
    const float* __restrict__ bb, const int* __restrict__ widths,
    float* __restrict__ xw) {
  const int b = blockIdx.z;
  const int t0 = blockIdx.y * 64;
  if (t0 >= widths[b]) return;  // recurrence only reads t < width
  const int g0 = blockIdx.x * 64;
  __shared__ __align__(16) float ht[128][64];
  __shared__ __align__(16) float wt[128][64];
  const int tid = threadIdx.x;
  const float* __restrict__ Wsrc = (g0 < 128) ? (Wf + g0) : (Wb + (g0 - 128));
  const float* __restrict__ bsrc = (g0 < 128) ? (bf + g0) : (bb + (g0 - 128));
  const float* hb = h + (size_t)b * HH * WW + t0;
#pragma unroll
  for (int i = 0; i < 8; ++i) {
    const int idx = tid + i * 256;  // 0..2047
    const int row = idx >> 4, c4 = (idx & 15) * 4;
    *(float4*)&ht[row][c4] = *(const float4*)&hb[(size_t)row * WW + c4];
    *(float4*)&wt[row][c4] = *(const float4*)&Wsrc[row * 128 + c4];
  }
  __syncthreads();
  const int tg = (tid & 15) * 4;
  const int tt = (tid >> 4) * 4;
  float acc[4][4];
#pragma unroll
  for (int i = 0; i < 4; ++i)
#pragma unroll
    for (int j = 0; j < 4; ++j) acc[i][j] = 0.f;
#pragma unroll 8
  for (int k = 0; k < 128; ++k) {
    const float4 av = *(const float4*)&ht[k][tt];
    const float4 wv = *(const float4*)&wt[k][tg];
    const float aarr[4] = {av.x, av.y, av.z, av.w};
    const float warr[4] = {wv.x, wv.y, wv.z, wv.w};
#pragma unroll
    for (int i = 0; i < 4; ++i)
#pragma unroll
      for (int j = 0; j < 4; ++j) acc[i][j] = fmaf(aarr[i], warr[j], acc[i][j]);
  }
  const float4 bias = *(const float4*)&bsrc[tg];
#pragma unroll
  for (int i = 0; i < 4; ++i) {
    float4 r;
    r.x = acc[i][0] + bias.x;
    r.y = acc[i][1] + bias.y;
    r.z = acc[i][2] + bias.z;
    r.w = acc[i][3] + bias.w;
    *(float4*)&xw[((size_t)b * WW + t0 + tt + i) * 256 + g0 + tg] = r;
  }
}

// -------------------------------------------------------- LSTM recurrence
// One wave per (batch, direction) chain. Lane j owns gate columns j and j+64.
// z layout [i(0:32) f(32:64) g(64:96) o(96:128)]:
// low lane u: z1=i_u, z2=g_u ; high lane u+32: z1=f_u, z2=o_u.
// Round-5 counters (VGPR=52 unchanged, 970 cyc/step) => weights were NOT
// VGPR-resident. This version: (a) every k-index is a compile-time literal
// (macro-expanded, zero rolled loops), (b) waves_per_eu(1,1) frees the full
// 512-VGPR budget, (c) permlane32_swap replaces LDS-pipe shfl_xor.
__global__ __attribute__((amdgpu_flat_work_group_size(64, 64)))
__attribute__((amdgpu_waves_per_eu(1, 1))) void k_lstm(
    const float* __restrict__ xw, const float* __restrict__ Uf,
    const float* __restrict__ Ub, const int* __restrict__ widths,
    float* __restrict__ outF, float* __restrict__ outB) {
  const int chain = blockIdx.x;
  const int b = chain >> 1, dir = chain & 1;
  const int width = widths[b];
  const int lane = threadIdx.x;
  const bool low = lane < 32;
  const float* __restrict__ U = dir ? Ub : Uf;
  float u1[UNITS], u2[UNITS];
#define LDU(k)                  \
  u1[k] = U[(k)*128 + lane];    \
  u2[k] = U[(k)*128 + 64 + lane];
  REP32(LDU)
#undef LDU
  // s2 activation: low = tanh (2*sig(2x)-1), high = sigmoid
  const float M2 = low ? (-2.f * L2E) : (-L2E);
  const float A2 = low ? 2.f : 1.f;
  const float B2 = low ? -1.f : 0.f;
  float* __restrict__ outp = dir ? outB : outF;

  const int t_first = dir ? (width - 1) : 0;
  const long sstep = dir ? -256 : 256;  // xw elements per time step
  const float* p0 = xw + ((size_t)b * WW) * 256 + dir * 128 + lane + (long)t_first * 256;

  float c = 0.f, hv = 0.f;
  float hs[UNITS];  // wave-uniform (readlane results) -> SGPRs
#define ZHS(k) hs[k] = 0.f;
  REP32(ZHS)
#undef ZHS

  float A0[4], B0[4], A1[4], B1[4];

#define LOADG(Aa, Bb, gg)                              \
  do {                                                 \
    const float* pg_ = p0 + (long)((gg)*4) * sstep;    \
    (Aa)[0] = pg_[0]; (Bb)[0] = pg_[64]; pg_ += sstep; \
    (Aa)[1] = pg_[0]; (Bb)[1] = pg_[64]; pg_ += sstep; \
    (Aa)[2] = pg_[0]; (Bb)[2] = pg_[64]; pg_ += sstep; \
    (Aa)[3] = pg_[0]; (Bb)[3] = pg_[64];               \
  } while (0)

#define FMG(k)                          \
  s0a = fmaf(hs[(k) + 0], u1[(k) + 0], s0a); \
  s0b = fmaf(hs[(k) + 1], u1[(k) + 1], s0b); \
  s0c = fmaf(hs[(k) + 2], u1[(k) + 2], s0c); \
  s0d = fmaf(hs[(k) + 3], u1[(k) + 3], s0d); \
  s1a = fmaf(hs[(k) + 0], u2[(k) + 0], s1a); \
  s1b = fmaf(hs[(k) + 1], u2[(k) + 1], s1b); \
  s1c = fmaf(hs[(k) + 2], u2[(k) + 2], s1c); \
  s1d = fmaf(hs[(k) + 3], u2[(k) + 3], s1d);

#define RDL(k) hs[k] = rdlane(hv, k);

#define STEP1(Ai, Bi, ss)                                                     \
  do {                                                                        \
    if ((ss) < width) { /* wave-uniform */                                    \
      float s0a = 0.f, s0b = 0.f, s0c = 0.f, s0d = 0.f;                       \
      float s1a = 0.f, s1b = 0.f, s1c = 0.f, s1d = 0.f;                       \
      FMG(0) FMG(4) FMG(8) FMG(12) FMG(16) FMG(20) FMG(24) FMG(28)            \
      const float z1 = (Ai) + ((s0a + s0b) + (s0c + s0d));                    \
      const float z2 = (Bi) + ((s1a + s1b) + (s1c + s1d));                    \
      const float sg1 = rcp_fast(1.f + exp2_fast(z1 * (-L2E)));               \
      const float r2_ = rcp_fast(1.f + exp2_fast(z2 * M2));                   \
      const float sg2 = fmaf(A2, r2_, B2);                                    \
      float X_, Y_, Z_, W_;                                                   \
      halfswap(sg1, sg2, X_, Y_);  /* X=[g2.hi|g1.hi] Y=[g2.lo|g1.lo] */      \
      halfswap(sg2, sg1, Z_, W_);  /* Z=[g1.hi|g2.hi] W=[g1.lo|g2.lo] */      \
      const float gi_ = low ? sg1 : Y_;                                       \
      const float gf_ = low ? Z_ : sg1;                                       \
      const float gg_ = low ? sg2 : W_;                                       \
      const float go_ = low ? X_ : sg2;                                       \
      c = fmaf(gf_, c, gi_ * gg_);                                            \
      const float th_ =                                                       \
          fmaf(2.f, rcp_fast(1.f + exp2_fast(c * (-2.f * L2E))), -1.f);       \
      hv = go_ * th_;                                                         \
      const int t_ = dir ? (width - 1 - (ss)) : (ss);                         \
      if (low) outp[((size_t)b * WW + t_) * UNITS + lane] = hv;               \
      REP32(RDL)                                                              \
    }                                                                         \
  } while (0)

#define STEPS4(Aa, Bb, gg)                 \
  do {                                     \
    STEP1((Aa)[0], (Bb)[0], (gg)*4 + 0);   \
    STEP1((Aa)[1], (Bb)[1], (gg)*4 + 1);   \
    STEP1((Aa)[2], (Bb)[2], (gg)*4 + 2);   \
    STEP1((Aa)[3], (Bb)[3], (gg)*4 + 3);   \
  } while (0)

  const int ngroups = (width + 3) >> 2;
  LOADG(A0, B0, 0);
  for (int g = 0; g < ngroups; g += 2) {
    if (g + 1 < ngroups) LOADG(A1, B1, g + 1);
    STEPS4(A0, B0, g);
    if (g + 1 < ngroups) {
      if (g + 2 < ngroups) LOADG(A0, B0, g + 2);
      STEPS4(A1, B1, g + 1);
    }
  }
#undef LOADG
#undef FMG
#undef RDL
#undef STEP1
#undef STEPS4
}

// ------------------------------------------- dense(32->201) + softmax + mask
__global__ __launch_bounds__(256, 1) void k_dense(
    const float* __restrict__ outF, const float* __restrict__ outB,
    const float* __restrict__ Wd, const float* __restrict__ bd,
    const int* __restrict__ widths, float* __restrict__ out) {
  const int lane = threadIdx.x & 63;
  const int gw = (int)((blockIdx.x * blockDim.x + threadIdx.x) >> 6);
  const int nw = (int)((gridDim.x * blockDim.x) >> 6);
  const int v0 = lane, v1 = lane + 64, v2 = lane + 128, v3 = lane + 192;
  const bool val3 = v3 < VOCAB;
  float w0[UNITS], w1[UNITS], w2[UNITS], w3[UNITS];
#pragma unroll
  for (int k = 0; k < UNITS; ++k) {
    w0[k] = Wd[k * VOCAB + v0];
    w1[k] = Wd[k * VOCAB + v1];
    w2[k] = Wd[k * VOCAB + v2];
    w3[k] = val3 ? Wd[k * VOCAB + v3] : 0.f;
  }
  const float b0 = bd[v0], b1 = bd[v1], b2 = bd[v2], b3 = val3 ? bd[v3] : 0.f;
  const int total = BB * WW;
  for (int t = gw; t < total; t += nw) {
    const int bb_ = t >> 11, tt = t & (WW - 1);
    float* o = out + (size_t)t * VOCAB;
    if (tt >= widths[bb_]) {
      o[v0] = 0.f; o[v1] = 0.f; o[v2] = 0.f;
      if (val3) o[v3] = 0.f;
      continue;
    }
    float mk = 0.f;
    if (lane < UNITS)
      mk = outF[(size_t)t * UNITS + lane] + outB[(size_t)t * UNITS + lane];
    float l0 = b0, l1 = b1, l2 = b2, l3 = b3;
#pragma unroll
    for (int k = 0; k < UNITS; ++k) {
      const float hkk = rdlane(mk, k);
      l0 = fmaf(hkk, w0[k], l0);
      l1 = fmaf(hkk, w1[k], l1);
      l2 = fmaf(hkk, w2[k], l2);
      l3 = fmaf(hkk, w3[k], l3);
    }
    if (!val3) l3 = -3.0e38f;
    float mx = fmaxf(fmaxf(l0, l1), fmaxf(l2, l3));
#pragma unroll
    for (int off = 32; off >= 1; off >>= 1) mx = fmaxf(mx, __shfl_xor(mx, off, 64));
    const float e0 = exp2_fast((l0 - mx) * L2E);
    const float e1 = exp2_fast((l1 - mx) * L2E);
    const float e2 = exp2_fast((l2 - mx) * L2E);
    const float e3 = val3 ? exp2_fast((l3 - mx) * L2E) : 0.f;
    float s = ((e0 + e1) + (e2 + e3));
#pragma unroll
    for (int off = 32; off >= 1; off >>= 1) s += __shfl_xor(s, off, 64);
    const float r = rcp_fast(s);
    o[v0] = e0 * r;
    o[v1] = e1 * r;
    o[v2] = e2 * r;
    if (val3) o[v3] = e3 * r;
  }
}

extern "C" void kernel_launch(void* const* d_in, const int* in_sizes, int n_in,
                              void* d_out, int out_size, void* d_ws, size_t ws_size,
                              hipStream_t stream) {
  const float* x  = (const float*)d_in[0];
  const float* ck = (const float*)d_in[1];
  const float* Wf = (const float*)d_in[2];
  const float* Uf = (const float*)d_in[3];
  const float* bf = (const float*)d_in[4];
  const float* Wb = (const float*)d_in[5];
  const float* Ub = (const float*)d_in[6];
  const float* bb = (const float*)d_in[7];
  const float* Wd = (const float*)d_in[8];
  const float* bd = (const float*)d_in[9];
  const int* widths = (const int*)d_in[10];
  float* out = (float*)d_out;
  char* ws = (char*)d_ws;
  // ws layout (fp32): h_conv 64MiB | xw 128MiB | out_f 16MiB | out_b 16MiB
  float* h  = (float*)(ws);
  float* xw = (float*)(ws + 67108864);
  float* oF = (float*)(ws + 67108864 + 134217728);
  float* oB = (float*)(ws + 67108864 + 134217728 + 16777216);

  k_conv<<<dim3(WW / 256, HH, BB), 256, 0, stream>>>(x, ck, widths, h);
  k_xw<<<dim3(4, WW / 64, BB), 256, 0, stream>>>(h, Wf, Wb, bf, bb, widths, xw);
  k_lstm<<<dim3(2 * BB), 64, 0, stream>>>(xw, Uf, Ub, widths, oF, oB);
  k_dense<<<dim3(1024), 256, 0, stream>>>(oF, oB, Wd, bd, widths, out);
}